// Round 1
// baseline (241.494 us; speedup 1.0000x reference)
//
#include <hip/hip_runtime.h>
#include <cstdint>
#include <cmath>

// Problem constants
#define B_    8
#define NHID_ 256
#define L_    2048
#define D_    512      // q/k/v channels (8 heads x 64)
#define DO_   2048     // output channels
#define QKVN  1536     // concat q|k|v

using u16    = unsigned short;
using short8 = __attribute__((ext_vector_type(8))) short;  // 8 bf16 (4 VGPRs)
using f32x4  = __attribute__((ext_vector_type(4))) float;  // 4 fp32 acc

typedef __attribute__((address_space(1))) void gv_t;
typedef __attribute__((address_space(3))) void lv_t;

__device__ inline void llds16(const void* g, void* l) {
  // async global->LDS, 16B/lane; LDS dest = wave-uniform base + lane*16
  __builtin_amdgcn_global_load_lds((const gv_t*)g, (lv_t*)l, 16, 0, 0);
}

__device__ inline u16 f32_to_bf16(float f) {
  unsigned u = __float_as_uint(f);
  u += 0x7fffu + ((u >> 16) & 1u);   // RNE (values finite)
  return (u16)(u >> 16);
}

__device__ inline void load8(const u16* p, float f[8]) {
  uint4 u = *reinterpret_cast<const uint4*>(p);
  f[0] = __uint_as_float(u.x << 16); f[1] = __uint_as_float(u.x & 0xffff0000u);
  f[2] = __uint_as_float(u.y << 16); f[3] = __uint_as_float(u.y & 0xffff0000u);
  f[4] = __uint_as_float(u.z << 16); f[5] = __uint_as_float(u.z & 0xffff0000u);
  f[6] = __uint_as_float(u.w << 16); f[7] = __uint_as_float(u.w & 0xffff0000u);
}

// ---------------------------------------------------------------------------
// prep (single launch): fp32 [R][C] -> bf16 [C][R] transposes for x and all
// weights, plus bias concat. Flat grid, block-uniform branch per tile range.
// block (32,8).
// ---------------------------------------------------------------------------
template <int R, int C>
__device__ inline void t32(const float* __restrict__ src, u16* __restrict__ dst,
                           int id, float (*tile)[33]) {
  constexpr int TPR = C / 32;              // tiles along cols
  constexpr int PER = (R / 32) * TPR;      // tiles per z-slice
  int z = id / PER, rem = id % PER;
  int ry = rem / TPR, cx = rem % TPR;
  src += (size_t)z * R * C;
  dst += (size_t)z * R * C;
  int c0 = cx * 32, r0 = ry * 32;
  int tx = threadIdx.x, ty = threadIdx.y;
#pragma unroll
  for (int i = 0; i < 4; ++i)
    tile[ty + i * 8][tx] = src[(size_t)(r0 + ty + i * 8) * C + c0 + tx];
  __syncthreads();
#pragma unroll
  for (int i = 0; i < 4; ++i)
    dst[(size_t)(c0 + ty + i * 8) * R + r0 + tx] = f32_to_bf16(tile[tx][ty + i * 8]);
}

// block-id ranges
#define PREP_X0   0
#define PREP_WQ   4096     // x: 8 * (256/32) * (2048/32) = 4096 tiles
#define PREP_WK   4224     // Wq: (256/32)*(512/32) = 128 tiles
#define PREP_WV   4352
#define PREP_WO   4480
#define PREP_BIAS 5504     // Wo: (512/32)*(2048/32) = 1024 tiles
#define PREP_NB   5510     // bias: 1536/256 = 6 blocks

__global__ void prep_all(const float* __restrict__ x,
                         const float* __restrict__ Wq, const float* __restrict__ Wk,
                         const float* __restrict__ Wv, const float* __restrict__ Wo,
                         const float* __restrict__ bq, const float* __restrict__ bk,
                         const float* __restrict__ bv,
                         u16* __restrict__ xb, u16* __restrict__ wqkvT,
                         u16* __restrict__ woT, float* __restrict__ bqkv) {
  __shared__ float tile[32][33];
  int bid = blockIdx.x;
  if (bid < PREP_WQ) {
    t32<NHID_, L_>(x, xb, bid, tile);
  } else if (bid < PREP_WK) {
    t32<NHID_, D_>(Wq, wqkvT, bid - PREP_WQ, tile);
  } else if (bid < PREP_WV) {
    t32<NHID_, D_>(Wk, wqkvT + 512 * NHID_, bid - PREP_WK, tile);
  } else if (bid < PREP_WO) {
    t32<NHID_, D_>(Wv, wqkvT + 1024 * NHID_, bid - PREP_WV, tile);
  } else if (bid < PREP_BIAS) {
    t32<D_, DO_>(Wo, woT, bid - PREP_WO, tile);
  } else {
    int d = (bid - PREP_BIAS) * 256 + threadIdx.y * 32 + threadIdx.x;
    float v = (d < 512) ? bq[d] : (d < 1024 ? bk[d - 512] : bv[d - 1024]);
    bqkv[d] = v;
  }
}

// ---------------------------------------------------------------------------
// 256x256 8-phase A*B^T GEMM core (T2+T3+T4+T5), plain HIP.
// A [M][K], B [N][K] bf16 row-major. 512 threads = 8 waves (2M x 4N); each
// wave owns a 128x64 C strip -> acc[8][4] f32x4.
//
// LDS (128 KiB): A,B each 2 dbuf x 2 phase-local halves x 128 rows x 64k bf16.
//   A-half mh = rows {wm*128 + mh*64 + q} laid out [wm][q]  (read only when
//   phase.mh == mh); B-half nh = rows {wn*64 + nh*32 + q} laid out [wn][q]
//   (read only when phase.nh == nh).
// Phase order per K-tile: (mh,nh) = (0,0)(0,1)(1,0)(1,1). Deaths: Ah0 after
// ph1, Bh0 after ph2, Ah1/Bh1 after ph3 -> half j of tile T staged at global
// phase 4T+j-6 (order Ah0,Bh0,Ah1,Bh1), one half-tile (2 loads/thread) per
// phase. Counted s_waitcnt vmcnt(4) once per K-tile (end of ph3) confirms the
// NEXT tile landed; vmcnt(0) only at the tail. Raw s_barrier everywhere
// (__syncthreads would force-drain vmcnt and re-create the m97 stall).
//
// k-chunk swizzle: chunk c (16B) of LDS row q lives at slot c^(q&7) ->
// ds_read_b128 fragments hit 8 distinct bank-quads x 2 lanes (free 2-way).
// ---------------------------------------------------------------------------
template <int K>
__device__ inline void gemm256(const u16* __restrict__ gA, const u16* __restrict__ gB,
                               int m0, int n0, char* ldsA, char* ldsB,
                               f32x4 (&acc)[8][4]) {
  constexpr int NT = K / 64;                     // K-tiles
  const int tid = threadIdx.x;
  const int wid = tid >> 6, lane = tid & 63;
  const int wm = wid >> 2, wn = wid & 3;
  const int fr = lane & 15, kq = lane >> 4;
  const int r8 = lane >> 3;
  const int kco = ((lane & 7) ^ r8) * 8;         // staging k-elem offset (swizzle)
  const int fx = fr & 7;
  const int s0 = (kq ^ fx) * 16;                 // ks=0 read slot byte; ks=1 = s0^64
  const int baseA = wm * 8192 + fr * 128;        // per-thread LDS read bases
  const int baseB = wn * 4096 + fr * 128;

  auto stageA = [&](int t, int h) {
    char* base = ldsA + (t & 1) * 32768 + h * 16384;
    const u16* g = gA + t * 64 + kco;
#pragma unroll
    for (int i = 0; i < 2; ++i) {
      int c = wid * 2 + i;                       // 16 chunks of 1KB per half
      int grow = m0 + (c >> 3) * 128 + h * 64 + (c & 7) * 8 + r8;
      llds16(g + (size_t)grow * K, base + c * 1024);
    }
  };
  auto stageB = [&](int t, int h) {
    char* base = ldsB + (t & 1) * 32768 + h * 16384;
    const u16* g = gB + t * 64 + kco;
#pragma unroll
    for (int i = 0; i < 2; ++i) {
      int c = wid * 2 + i;
      int grow = n0 + (c >> 2) * 64 + h * 32 + (c & 3) * 8 + r8;
      llds16(g + (size_t)grow * K, base + c * 1024);
    }
  };
  auto stageH = [&](int H) {                     // linear half-tile schedule
    if (H >= 4 * NT) return;                     // epilogue: nothing left
    int t = H >> 2, j = H & 3;
    if (j == 0) stageA(t, 0);
    else if (j == 1) stageB(t, 0);
    else if (j == 2) stageA(t, 1);
    else stageB(t, 1);
  };

#pragma unroll
  for (int i = 0; i < 8; ++i)
#pragma unroll
    for (int j = 0; j < 4; ++j) acc[i][j] = f32x4{0.f, 0.f, 0.f, 0.f};

  // prologue: tile0 complete + tile1's first 2 halves in flight
  stageH(0); stageH(1); stageH(2); stageH(3); stageH(4); stageH(5);
  asm volatile("s_waitcnt vmcnt(4)" ::: "memory");   // tile0 landed
  __builtin_amdgcn_s_barrier();
  asm volatile("" ::: "memory");

  for (int t = 0; t < NT; ++t) {
    const char* bA = ldsA + (t & 1) * 32768;
    const char* bB = ldsB + (t & 1) * 32768;
#pragma unroll
    for (int ph = 0; ph < 4; ++ph) {
      const int mh = ph >> 1, nh = ph & 1;
      // ds-read this phase's quadrant fragments (12 x ds_read_b128)
      short8 a[4][2], b[2][2];
#pragma unroll
      for (int ks = 0; ks < 2; ++ks) {
        const int sl = s0 ^ (ks * 64);
#pragma unroll
        for (int mt = 0; mt < 4; ++mt)
          a[mt][ks] = *(const short8*)(bA + mh * 16384 + baseA + mt * 2048 + sl);
#pragma unroll
        for (int nt = 0; nt < 2; ++nt)
          b[nt][ks] = *(const short8*)(bB + nh * 16384 + baseB + nt * 2048 + sl);
      }
      // one half-tile prefetch (2 x global_load_lds), overwrites a dead half
      stageH(t * 4 + ph + 6);
      __builtin_amdgcn_s_barrier();
      asm volatile("s_waitcnt lgkmcnt(0)" ::: "memory");
      __builtin_amdgcn_s_setprio(1);
#pragma unroll
      for (int ks = 0; ks < 2; ++ks)
#pragma unroll
        for (int mt = 0; mt < 4; ++mt)
#pragma unroll
          for (int nt = 0; nt < 2; ++nt)
            acc[mh * 4 + mt][nh * 2 + nt] = __builtin_amdgcn_mfma_f32_16x16x32_bf16(
                a[mt][ks], b[nt][ks], acc[mh * 4 + mt][nh * 2 + nt], 0, 0, 0);
      __builtin_amdgcn_s_setprio(0);
      if (ph == 3) {                             // counted wait: next tile landed
        if (t < NT - 2)       asm volatile("s_waitcnt vmcnt(4)" ::: "memory");
        else if (t == NT - 2) asm volatile("s_waitcnt vmcnt(0)" ::: "memory");
      }
      __builtin_amdgcn_s_barrier();
      asm volatile("" ::: "memory");
    }
  }
}

// QKV GEMM: C[bl][d] = xb[bl][c] * WqkvT[d][c] + bqkv[d], store bf16
__global__ __launch_bounds__(512, 2) void qkv_gemm(const u16* __restrict__ xb,
                                                   const u16* __restrict__ wT,
                                                   const float* __restrict__ bqkv,
                                                   u16* __restrict__ qkv) {
  __shared__ __align__(16) char ldsA[65536];
  __shared__ __align__(16) char ldsB[65536];
  int m0 = blockIdx.y * 256, n0 = blockIdx.x * 256;
  f32x4 acc[8][4];
  gemm256<NHID_>(xb, wT, m0, n0, ldsA, ldsB, acc);
  const int lane = threadIdx.x & 63, wid = threadIdx.x >> 6;
  const int wm = wid >> 2, wn = wid & 3;
  const int fr = lane & 15, kq = lane >> 4;
#pragma unroll
  for (int i = 0; i < 8; ++i) {
    int row = m0 + wm * 128 + i * 16 + kq * 4;
#pragma unroll
    for (int j = 0; j < 4; ++j) {
      int col = n0 + wn * 64 + j * 16 + fr;
      float bias = bqkv[col];
#pragma unroll
      for (int r = 0; r < 4; ++r)
        qkv[(size_t)(row + r) * QKVN + col] = f32_to_bf16(acc[i][j][r] + bias);
    }
  }
}

// Out GEMM (swapped): C[j][l] = WoT[j][c] * att[b*L+l][c] + bo[j], fp32 store
// to out[b][j][l] -- coalesced along l (MFMA C col = lane&15).
__global__ __launch_bounds__(512, 2) void out_gemm(const u16* __restrict__ woT,
                                                   const u16* __restrict__ att,
                                                   const float* __restrict__ bo,
                                                   float* __restrict__ out) {
  __shared__ __align__(16) char ldsA[65536];
  __shared__ __align__(16) char ldsB[65536];
  int b = blockIdx.z;
  int m0 = blockIdx.y * 256;   // j
  int n0 = blockIdx.x * 256;   // l
  const u16* gB = att + (size_t)b * L_ * D_;
  f32x4 acc[8][4];
  gemm256<D_>(woT, gB, m0, n0, ldsA, ldsB, acc);
  const int lane = threadIdx.x & 63, wid = threadIdx.x >> 6;
  const int wm = wid >> 2, wn = wid & 3;
  const int fr = lane & 15, kq = lane >> 4;
  float* outb = out + (size_t)b * DO_ * L_;
#pragma unroll
  for (int i = 0; i < 8; ++i) {
    int row = m0 + wm * 128 + i * 16 + kq * 4;
#pragma unroll
    for (int r = 0; r < 4; ++r) {
      float bias = bo[row + r];
#pragma unroll
      for (int j = 0; j < 4; ++j) {
        int col = n0 + wn * 64 + j * 16 + fr;
        outb[(size_t)(row + r) * L_ + col] = acc[i][j][r] + bias;
      }
    }
  }
}

// ---------------------------------------------------------------------------
// Windowed attention: one wave per (b,l). lane -> (head = lane>>3, 8 channels).
// OOB windows use k=v=0 and PARTICIPATE in softmax with score 0 (matches the
// reference's zero-padded extract_patches semantics).
// ---------------------------------------------------------------------------
__global__ __launch_bounds__(256) void attn_kernel(const u16* __restrict__ qkv,
                                                   u16* __restrict__ att) {
  const int wave = threadIdx.x >> 6, lane = threadIdx.x & 63;
  const int bl = blockIdx.x * 4 + wave;
  const int l = bl & (L_ - 1);
  const int c0 = (lane >> 3) * 64 + (lane & 7) * 8;   // channel base, 8 per lane

  float q[8];
  load8(qkv + (size_t)bl * QKVN + c0, q);

  float kk[3][8], vv[3][8];
#pragma unroll
  for (int w = 0; w < 3; ++w) {
    int lw = l + w - 1;
    if (lw >= 0 && lw < L_) {
      const u16* base = qkv + (size_t)(bl + w - 1) * QKVN;
      load8(base + 512 + c0, kk[w]);
      load8(base + 1024 + c0, vv[w]);
    } else {
#pragma unroll
      for (int t = 0; t < 8; ++t) { kk[w][t] = 0.f; vv[w][t] = 0.f; }
    }
  }

  float s[3];
#pragma unroll
  for (int w = 0; w < 3; ++w) {
    float a = 0.f;
#pragma unroll
    for (int t = 0; t < 8; ++t) a = fmaf(q[t], kk[w][t], a);
    s[w] = a;
  }
  // reduce over the 8 lanes of this head (butterfly; all lanes end with sum)
#pragma unroll
  for (int off = 1; off < 8; off <<= 1) {
    s[0] += __shfl_xor(s[0], off);
    s[1] += __shfl_xor(s[1], off);
    s[2] += __shfl_xor(s[2], off);
  }
  s[0] *= 0.125f; s[1] *= 0.125f; s[2] *= 0.125f;   // 1/sqrt(64)

  float mx = fmaxf(s[0], fmaxf(s[1], s[2]));
  float e0 = __expf(s[0] - mx), e1 = __expf(s[1] - mx), e2 = __expf(s[2] - mx);
  float inv = 1.f / (e0 + e1 + e2);
  float a0 = e0 * inv, a1 = e1 * inv, a2 = e2 * inv;

  u16 o16[8];
#pragma unroll
  for (int t = 0; t < 8; ++t) {
    float o = a0 * vv[0][t] + a1 * vv[1][t] + a2 * vv[2][t];
    o16[t] = f32_to_bf16(o);
  }
  uint4 pk;
  pk.x = (unsigned)o16[0] | ((unsigned)o16[1] << 16);
  pk.y = (unsigned)o16[2] | ((unsigned)o16[3] << 16);
  pk.z = (unsigned)o16[4] | ((unsigned)o16[5] << 16);
  pk.w = (unsigned)o16[6] | ((unsigned)o16[7] << 16);
  *reinterpret_cast<uint4*>(att + (size_t)bl * D_ + c0) = pk;
}

// ---------------------------------------------------------------------------
extern "C" void kernel_launch(void* const* d_in, const int* in_sizes, int n_in,
                              void* d_out, int out_size, void* d_ws, size_t ws_size,
                              hipStream_t stream) {
  const float* x  = (const float*)d_in[0];
  const float* Wq = (const float*)d_in[1];
  const float* bq = (const float*)d_in[2];
  const float* Wk = (const float*)d_in[3];
  const float* bk = (const float*)d_in[4];
  const float* Wv = (const float*)d_in[5];
  const float* bv = (const float*)d_in[6];
  const float* Wo = (const float*)d_in[7];
  const float* bo = (const float*)d_in[8];
  float* out = (float*)d_out;

  char* ws = (char*)d_ws;
  // workspace layout (bytes)
  u16*   xb    = (u16*)(ws + 0);            //  16384x256  bf16  (8388608)
  u16*   wqkvT = (u16*)(ws + 8388608);      //  1536x256   bf16  (786432)
  u16*   woT   = (u16*)(ws + 9175040);      //  2048x512   bf16  (2097152)
  float* bqkv  = (float*)(ws + 11272192);   //  1536       f32   (6144)
  u16*   qkv   = (u16*)(ws + 11278336);     //  16384x1536 bf16  (50331648)
  u16*   att   = (u16*)(ws + 61609984);     //  16384x512  bf16  (16777216)
  // total ~78.4 MB

  // all transposes + bias in ONE launch
  prep_all<<<PREP_NB, dim3(32, 8), 0, stream>>>(x, Wq, Wk, Wv, Wo, bq, bk, bv,
                                                xb, wqkvT, woT, bqkv);

  // QKV projection: [16384 x 1536] = xb [16384x256] * wqkvT^T  (256^2 8-phase)
  qkv_gemm<<<dim3(QKVN / 256, (B_ * L_) / 256), 512, 0, stream>>>(xb, wqkvT, bqkv, qkv);

  // windowed softmax attention -> att [16384x512] bf16
  attn_kernel<<<(B_ * L_) / 4, 256, 0, stream>>>(qkv, att);

  // output projection, transposed store: out[b][j][l]  (256^2 8-phase)
  out_gemm<<<dim3(L_ / 256, DO_ / 256, B_), 512, 0, stream>>>(woT, att, bo, out);
}

// Round 2
// 220.252 us; speedup vs baseline: 1.0964x; 1.0964x over previous
//
#include <hip/hip_runtime.h>
#include <cstdint>
#include <cmath>

// Problem constants
#define B_    8
#define NHID_ 256
#define L_    2048
#define D_    512      // q/k/v channels (8 heads x 64)
#define DO_   2048     // output channels
#define QKVN  1536     // concat q|k|v

using u16    = unsigned short;
using short8 = __attribute__((ext_vector_type(8))) short;  // 8 bf16 (4 VGPRs)
using f32x4  = __attribute__((ext_vector_type(4))) float;  // 4 fp32 acc

typedef __attribute__((address_space(1))) void gv_t;
typedef __attribute__((address_space(3))) void lv_t;

__device__ inline void llds16(const void* g, void* l) {
  // async global->LDS, 16B/lane; LDS dest = wave-uniform base + lane*16
  __builtin_amdgcn_global_load_lds((const gv_t*)g, (lv_t*)l, 16, 0, 0);
}

__device__ inline u16 f32_to_bf16(float f) {
  unsigned u = __float_as_uint(f);
  u += 0x7fffu + ((u >> 16) & 1u);   // RNE (values finite)
  return (u16)(u >> 16);
}

__device__ inline void load8(const u16* p, float f[8]) {
  uint4 u = *reinterpret_cast<const uint4*>(p);
  f[0] = __uint_as_float(u.x << 16); f[1] = __uint_as_float(u.x & 0xffff0000u);
  f[2] = __uint_as_float(u.y << 16); f[3] = __uint_as_float(u.y & 0xffff0000u);
  f[4] = __uint_as_float(u.z << 16); f[5] = __uint_as_float(u.z & 0xffff0000u);
  f[6] = __uint_as_float(u.w << 16); f[7] = __uint_as_float(u.w & 0xffff0000u);
}

// ---------------------------------------------------------------------------
// prep (single launch): fp32 [R][C] -> bf16 [C][R] transposes for x and all
// weights, plus bias concat. Flat grid, block-uniform branch per tile range.
// block (32,8).
// ---------------------------------------------------------------------------
template <int R, int C>
__device__ inline void t32(const float* __restrict__ src, u16* __restrict__ dst,
                           int id, float (*tile)[33]) {
  constexpr int TPR = C / 32;              // tiles along cols
  constexpr int PER = (R / 32) * TPR;      // tiles per z-slice
  int z = id / PER, rem = id % PER;
  int ry = rem / TPR, cx = rem % TPR;
  src += (size_t)z * R * C;
  dst += (size_t)z * R * C;
  int c0 = cx * 32, r0 = ry * 32;
  int tx = threadIdx.x, ty = threadIdx.y;
#pragma unroll
  for (int i = 0; i < 4; ++i)
    tile[ty + i * 8][tx] = src[(size_t)(r0 + ty + i * 8) * C + c0 + tx];
  __syncthreads();
#pragma unroll
  for (int i = 0; i < 4; ++i)
    dst[(size_t)(c0 + ty + i * 8) * R + r0 + tx] = f32_to_bf16(tile[tx][ty + i * 8]);
}

// block-id ranges
#define PREP_X0   0
#define PREP_WQ   4096     // x: 8 * (256/32) * (2048/32) = 4096 tiles
#define PREP_WK   4224     // Wq: (256/32)*(512/32) = 128 tiles
#define PREP_WV   4352
#define PREP_WO   4480
#define PREP_BIAS 5504     // Wo: (512/32)*(2048/32) = 1024 tiles
#define PREP_NB   5510     // bias: 1536/256 = 6 blocks

__global__ void prep_all(const float* __restrict__ x,
                         const float* __restrict__ Wq, const float* __restrict__ Wk,
                         const float* __restrict__ Wv, const float* __restrict__ Wo,
                         const float* __restrict__ bq, const float* __restrict__ bk,
                         const float* __restrict__ bv,
                         u16* __restrict__ xb, u16* __restrict__ wqkvT,
                         u16* __restrict__ woT, float* __restrict__ bqkv) {
  __shared__ float tile[32][33];
  int bid = blockIdx.x;
  if (bid < PREP_WQ) {
    t32<NHID_, L_>(x, xb, bid, tile);
  } else if (bid < PREP_WK) {
    t32<NHID_, D_>(Wq, wqkvT, bid - PREP_WQ, tile);
  } else if (bid < PREP_WV) {
    t32<NHID_, D_>(Wk, wqkvT + 512 * NHID_, bid - PREP_WK, tile);
  } else if (bid < PREP_WO) {
    t32<NHID_, D_>(Wv, wqkvT + 1024 * NHID_, bid - PREP_WV, tile);
  } else if (bid < PREP_BIAS) {
    t32<D_, DO_>(Wo, woT, bid - PREP_WO, tile);
  } else {
    int d = (bid - PREP_BIAS) * 256 + threadIdx.y * 32 + threadIdx.x;
    float v = (d < 512) ? bq[d] : (d < 1024 ? bk[d - 512] : bv[d - 1024]);
    bqkv[d] = v;
  }
}

// ---------------------------------------------------------------------------
// m97-style A*B^T GEMM core with XOR-swizzled LDS staging (round-0 proven).
// A [M][K], B [N][K] bf16 row-major (K contiguous), 128x128 tile, BK=64,
// 256 threads = 4 waves (2x2), 4x4 16x16x32 MFMA per wave. 32 KiB LDS ->
// 3+ blocks/CU; inter-block wave overlap hides the barrier drain (m114).
//
// Swizzle: global k-chunk c (8 elems = 16B) of tile-row r is staged at LDS
// slot c ^ (r&7). ds_read_b128 fragment reads then hit bank-quad
// ((fr&7)^C)*4 -> 8 distinct quads x 2 lanes = 2-way (free, m136).
// ---------------------------------------------------------------------------
#define BM 128
#define BN 128
#define BK 64

template <int K>
__device__ inline void gemm_tile(const u16* __restrict__ gA, const u16* __restrict__ gB,
                                 int m0, int n0, u16* As, u16* Bs, f32x4 (&acc)[4][4]) {
  const int tid = threadIdx.x;
  const int wave = tid >> 6, lane = tid & 63;
  const int wm = wave >> 1, wn = wave & 1;
  const int r8 = lane >> 3;                 // row within 8-row chunk
  const int kc = ((lane & 7) ^ r8) * 8;     // swizzled k element offset
  const int fr = lane & 15;                 // fragment row/col
  const int fx = fr & 7;                    // swizzle key for reads
  const int kq = lane >> 4;                 // fragment k-chunk 0..3

  auto stage = [&](int k0) {
#pragma unroll
    for (int t = 0; t < 4; ++t) {
      int chunk = wave * 4 + t;             // 16 chunks of 1KB per tile
      int row = chunk * 8 + r8;
      llds16(gA + (size_t)(m0 + row) * K + k0 + kc, (char*)As + chunk * 1024);
      llds16(gB + (size_t)(n0 + row) * K + k0 + kc, (char*)Bs + chunk * 1024);
    }
  };

  stage(0);                                 // overlap first staging with init
#pragma unroll
  for (int i = 0; i < 4; ++i)
#pragma unroll
    for (int j = 0; j < 4; ++j) acc[i][j] = f32x4{0.f, 0.f, 0.f, 0.f};

  for (int k0 = 0;;) {
    __syncthreads();                        // drains staging (vmcnt0 + barrier)
#pragma unroll
    for (int ks = 0; ks < 2; ++ks) {
      short8 a[4], b[4];
      const int slot = (((ks * 4 + kq) ^ fx)) * 8;
#pragma unroll
      for (int mt = 0; mt < 4; ++mt)
        a[mt] = *(const short8*)(As + (wm * 64 + mt * 16 + fr) * BK + slot);
#pragma unroll
      for (int nt = 0; nt < 4; ++nt)
        b[nt] = *(const short8*)(Bs + (wn * 64 + nt * 16 + fr) * BK + slot);
#pragma unroll
      for (int mt = 0; mt < 4; ++mt)
#pragma unroll
        for (int nt = 0; nt < 4; ++nt)
          acc[mt][nt] = __builtin_amdgcn_mfma_f32_16x16x32_bf16(a[mt], b[nt], acc[mt][nt], 0, 0, 0);
    }
    k0 += BK;
    if (k0 >= K) break;
    __syncthreads();                        // LDS reads done; safe to restage
    stage(k0);
  }
}

// QKV GEMM: C[bl][d] = xb[bl][c] * WqkvT[d][c] + bqkv[d], store bf16.
// 1D grid 1536 with bijective XCD chunking: XCD k owns m-panels [16k,16k+16)
// x all 12 n-tiles -> per-XCD L2 set = 16x64KB A-panels + full B (0.8MB)
// ~ 1.8 MB < 4 MB.
__global__ __launch_bounds__(256) void qkv_gemm(const u16* __restrict__ xb,
                                                const u16* __restrict__ wT,
                                                const float* __restrict__ bqkv,
                                                u16* __restrict__ qkv) {
  __shared__ __align__(16) u16 As[BM * BK];
  __shared__ __align__(16) u16 Bs[BN * BK];
  int id = blockIdx.x;                      // 1536 blocks, %8==0
  int swz = (id & 7) * 192 + (id >> 3);     // bijective XCD chunking (T1)
  int n0 = (swz % 12) * BN;
  int m0 = (swz / 12) * BM;
  f32x4 acc[4][4];
  gemm_tile<NHID_>(xb, wT, m0, n0, As, Bs, acc);
  const int lane = threadIdx.x & 63, wave = threadIdx.x >> 6;
  const int wm = wave >> 1, wn = wave & 1;
#pragma unroll
  for (int mt = 0; mt < 4; ++mt) {
    int row0 = m0 + wm * 64 + mt * 16 + (lane >> 4) * 4;
#pragma unroll
    for (int nt = 0; nt < 4; ++nt) {
      int col = n0 + wn * 64 + nt * 16 + (lane & 15);
      float bias = bqkv[col];
#pragma unroll
      for (int r = 0; r < 4; ++r)
        qkv[(size_t)(row0 + r) * QKVN + col] = f32_to_bf16(acc[mt][nt][r] + bias);
    }
  }
}

// Out GEMM (swapped): C[j][l] = WoT[j][c] * att[b*L+l][c] + bo[j], fp32 store
// to out[b][j][l] -- coalesced along l (MFMA C col = lane&15).
// 1D grid 2048 with XCD chunking: XCD k owns exactly b=k (256 blocks) ->
// per-XCD L2 set = att[b] (2MB) + woT (2MB) = 4MB.
__global__ __launch_bounds__(256) void out_gemm(const u16* __restrict__ woT,
                                                const u16* __restrict__ att,
                                                const float* __restrict__ bo,
                                                float* __restrict__ out) {
  __shared__ __align__(16) u16 As[BM * BK];
  __shared__ __align__(16) u16 Bs[BN * BK];
  int id = blockIdx.x;                      // 2048 blocks, %8==0
  int swz = (id & 7) * 256 + (id >> 3);     // bijective XCD chunking (T1)
  int b = swz >> 8;
  int rem = swz & 255;
  int m0 = (rem >> 4) * BM;                 // j-panel
  int n0 = (rem & 15) * BN;                 // l-tile
  const u16* gB = att + (size_t)b * L_ * D_;
  f32x4 acc[4][4];
  gemm_tile<D_>(woT, gB, m0, n0, As, Bs, acc);
  const int lane = threadIdx.x & 63, wave = threadIdx.x >> 6;
  const int wm = wave >> 1, wn = wave & 1;
  float* outb = out + (size_t)b * DO_ * L_;
#pragma unroll
  for (int mt = 0; mt < 4; ++mt) {
    int row0 = m0 + wm * 64 + mt * 16 + (lane >> 4) * 4;
#pragma unroll
    for (int r = 0; r < 4; ++r) {
      float bias = bo[row0 + r];
#pragma unroll
      for (int nt = 0; nt < 4; ++nt) {
        int col = n0 + wn * 64 + nt * 16 + (lane & 15);
        outb[(size_t)(row0 + r) * L_ + col] = acc[mt][nt][r] + bias;
      }
    }
  }
}

// ---------------------------------------------------------------------------
// Windowed attention: one wave per (b,l). lane -> (head = lane>>3, 8 channels).
// OOB windows use k=v=0 and PARTICIPATE in softmax with score 0 (matches the
// reference's zero-padded extract_patches semantics). 512 threads = 8 waves.
// ---------------------------------------------------------------------------
__global__ __launch_bounds__(512) void attn_kernel(const u16* __restrict__ qkv,
                                                   u16* __restrict__ att) {
  const int wave = threadIdx.x >> 6, lane = threadIdx.x & 63;
  const int bl = blockIdx.x * 8 + wave;
  const int l = bl & (L_ - 1);
  const int c0 = (lane >> 3) * 64 + (lane & 7) * 8;   // channel base, 8 per lane

  float q[8];
  load8(qkv + (size_t)bl * QKVN + c0, q);

  float kk[3][8], vv[3][8];
#pragma unroll
  for (int w = 0; w < 3; ++w) {
    int lw = l + w - 1;
    if (lw >= 0 && lw < L_) {
      const u16* base = qkv + (size_t)(bl + w - 1) * QKVN;
      load8(base + 512 + c0, kk[w]);
      load8(base + 1024 + c0, vv[w]);
    } else {
#pragma unroll
      for (int t = 0; t < 8; ++t) { kk[w][t] = 0.f; vv[w][t] = 0.f; }
    }
  }

  float s[3];
#pragma unroll
  for (int w = 0; w < 3; ++w) {
    float a = 0.f;
#pragma unroll
    for (int t = 0; t < 8; ++t) a = fmaf(q[t], kk[w][t], a);
    s[w] = a;
  }
  // reduce over the 8 lanes of this head (butterfly; all lanes end with sum)
#pragma unroll
  for (int off = 1; off < 8; off <<= 1) {
    s[0] += __shfl_xor(s[0], off);
    s[1] += __shfl_xor(s[1], off);
    s[2] += __shfl_xor(s[2], off);
  }
  s[0] *= 0.125f; s[1] *= 0.125f; s[2] *= 0.125f;   // 1/sqrt(64)

  float mx = fmaxf(s[0], fmaxf(s[1], s[2]));
  float e0 = __expf(s[0] - mx), e1 = __expf(s[1] - mx), e2 = __expf(s[2] - mx);
  float inv = 1.f / (e0 + e1 + e2);
  float a0 = e0 * inv, a1 = e1 * inv, a2 = e2 * inv;

  u16 o16[8];
#pragma unroll
  for (int t = 0; t < 8; ++t) {
    float o = a0 * vv[0][t] + a1 * vv[1][t] + a2 * vv[2][t];
    o16[t] = f32_to_bf16(o);
  }
  uint4 pk;
  pk.x = (unsigned)o16[0] | ((unsigned)o16[1] << 16);
  pk.y = (unsigned)o16[2] | ((unsigned)o16[3] << 16);
  pk.z = (unsigned)o16[4] | ((unsigned)o16[5] << 16);
  pk.w = (unsigned)o16[6] | ((unsigned)o16[7] << 16);
  *reinterpret_cast<uint4*>(att + (size_t)bl * D_ + c0) = pk;
}

// ---------------------------------------------------------------------------
extern "C" void kernel_launch(void* const* d_in, const int* in_sizes, int n_in,
                              void* d_out, int out_size, void* d_ws, size_t ws_size,
                              hipStream_t stream) {
  const float* x  = (const float*)d_in[0];
  const float* Wq = (const float*)d_in[1];
  const float* bq = (const float*)d_in[2];
  const float* Wk = (const float*)d_in[3];
  const float* bk = (const float*)d_in[4];
  const float* Wv = (const float*)d_in[5];
  const float* bv = (const float*)d_in[6];
  const float* Wo = (const float*)d_in[7];
  const float* bo = (const float*)d_in[8];
  float* out = (float*)d_out;

  char* ws = (char*)d_ws;
  // workspace layout (bytes)
  u16*   xb    = (u16*)(ws + 0);            //  16384x256  bf16  (8388608)
  u16*   wqkvT = (u16*)(ws + 8388608);      //  1536x256   bf16  (786432)
  u16*   woT   = (u16*)(ws + 9175040);      //  2048x512   bf16  (2097152)
  float* bqkv  = (float*)(ws + 11272192);   //  1536       f32   (6144)
  u16*   qkv   = (u16*)(ws + 11278336);     //  16384x1536 bf16  (50331648)
  u16*   att   = (u16*)(ws + 61609984);     //  16384x512  bf16  (16777216)
  // total ~78.4 MB

  // all transposes + bias in ONE launch
  prep_all<<<PREP_NB, dim3(32, 8), 0, stream>>>(x, Wq, Wk, Wv, Wo, bq, bk, bv,
                                                xb, wqkvT, woT, bqkv);

  // QKV projection: [16384 x 1536] = xb [16384x256] * wqkvT^T
  qkv_gemm<<<(QKVN / BN) * ((B_ * L_) / BM), 256, 0, stream>>>(xb, wqkvT, bqkv, qkv);

  // windowed softmax attention -> att [16384x512] bf16
  attn_kernel<<<(B_ * L_) / 8, 512, 0, stream>>>(qkv, att);

  // output projection, transposed store: out[b][j][l]
  out_gemm<<<(L_ / BN) * (DO_ / BM) * B_, 256, 0, stream>>>(woT, att, bo, out);
}

// Round 3
// 220.166 us; speedup vs baseline: 1.0969x; 1.0004x over previous
//
#include <hip/hip_runtime.h>
#include <cstdint>
#include <cmath>

// Problem constants
#define B_    8
#define NHID_ 256
#define L_    2048
#define D_    512      // q/k/v channels (8 heads x 64)
#define DO_   2048     // output channels
#define QKVN  1536     // concat q|k|v

using u16    = unsigned short;
using short8 = __attribute__((ext_vector_type(8))) short;  // 8 bf16 (4 VGPRs)
using f32x4  = __attribute__((ext_vector_type(4))) float;  // 4 fp32 acc

typedef __attribute__((address_space(1))) void gv_t;
typedef __attribute__((address_space(3))) void lv_t;

__device__ inline void llds16(const void* g, void* l) {
  // async global->LDS, 16B/lane; LDS dest = wave-uniform base + lane*16
  __builtin_amdgcn_global_load_lds((const gv_t*)g, (lv_t*)l, 16, 0, 0);
}

__device__ inline u16 f32_to_bf16(float f) {
  unsigned u = __float_as_uint(f);
  u += 0x7fffu + ((u >> 16) & 1u);   // RNE (values finite)
  return (u16)(u >> 16);
}

__device__ inline void load8(const u16* p, float f[8]) {
  uint4 u = *reinterpret_cast<const uint4*>(p);
  f[0] = __uint_as_float(u.x << 16); f[1] = __uint_as_float(u.x & 0xffff0000u);
  f[2] = __uint_as_float(u.y << 16); f[3] = __uint_as_float(u.y & 0xffff0000u);
  f[4] = __uint_as_float(u.z << 16); f[5] = __uint_as_float(u.z & 0xffff0000u);
  f[6] = __uint_as_float(u.w << 16); f[7] = __uint_as_float(u.w & 0xffff0000u);
}

// ---------------------------------------------------------------------------
// prep (single launch): fp32 [R][C] -> bf16 [C][R] transposes for x and all
// weights, plus bias concat. 64x64 tiles, block (64,8): 256B coalesced fp32
// loads, 128B bf16 store rows. LDS [64][65]: column reads hit (tx+c)%32 ->
// 2-way bank alias = free.
// ---------------------------------------------------------------------------
template <int R, int C>
__device__ inline void t64(const float* __restrict__ src, u16* __restrict__ dst,
                           int id, float (*tile)[65]) {
  constexpr int TPR = C / 64;              // tiles along cols
  constexpr int PER = (R / 64) * TPR;      // tiles per z-slice
  int z = id / PER, rem = id % PER;
  int ry = rem / TPR, cx = rem % TPR;
  src += (size_t)z * R * C;
  dst += (size_t)z * R * C;
  int c0 = cx * 64, r0 = ry * 64;
  int tx = threadIdx.x, ty = threadIdx.y;
#pragma unroll
  for (int i = 0; i < 8; ++i)
    tile[ty + i * 8][tx] = src[(size_t)(r0 + ty + i * 8) * C + c0 + tx];
  __syncthreads();
#pragma unroll
  for (int i = 0; i < 8; ++i)
    dst[(size_t)(c0 + ty + i * 8) * R + r0 + tx] = f32_to_bf16(tile[tx][ty + i * 8]);
}

// block-id ranges (64x64 tiles)
#define PREP_WQ   1024     // x: 8 * (256/64) * (2048/64) = 1024 tiles
#define PREP_WK   1056     // Wq: (256/64)*(512/64) = 32 tiles
#define PREP_WV   1088
#define PREP_WO   1120
#define PREP_BIAS 1376     // Wo: (512/64)*(2048/64) = 256 tiles
#define PREP_NB   1379     // bias: 1536/512 = 3 blocks

__global__ void prep_all(const float* __restrict__ x,
                         const float* __restrict__ Wq, const float* __restrict__ Wk,
                         const float* __restrict__ Wv, const float* __restrict__ Wo,
                         const float* __restrict__ bq, const float* __restrict__ bk,
                         const float* __restrict__ bv,
                         u16* __restrict__ xb, u16* __restrict__ wqkvT,
                         u16* __restrict__ woT, float* __restrict__ bqkv) {
  __shared__ float tile[64][65];
  int bid = blockIdx.x;
  if (bid < PREP_WQ) {
    t64<NHID_, L_>(x, xb, bid, tile);
  } else if (bid < PREP_WK) {
    t64<NHID_, D_>(Wq, wqkvT, bid - PREP_WQ, tile);
  } else if (bid < PREP_WV) {
    t64<NHID_, D_>(Wk, wqkvT + 512 * NHID_, bid - PREP_WK, tile);
  } else if (bid < PREP_WO) {
    t64<NHID_, D_>(Wv, wqkvT + 1024 * NHID_, bid - PREP_WV, tile);
  } else if (bid < PREP_BIAS) {
    t64<D_, DO_>(Wo, woT, bid - PREP_WO, tile);
  } else {
    int d = (bid - PREP_BIAS) * 512 + threadIdx.y * 64 + threadIdx.x;
    float v = (d < 512) ? bq[d] : (d < 1024 ? bk[d - 512] : bv[d - 1024]);
    bqkv[d] = v;
  }
}

// ---------------------------------------------------------------------------
// m97-style A*B^T GEMM core with XOR-swizzled LDS staging (round-0 proven).
// A [M][K], B [N][K] bf16 row-major (K contiguous), 128x128 tile, BK=64,
// 256 threads = 4 waves (2x2), 4x4 16x16x32 MFMA per wave. 32 KiB LDS ->
// 3+ blocks/CU; inter-block wave overlap hides the barrier drain (m114).
//
// Swizzle: global k-chunk c (8 elems = 16B) of tile-row r is staged at LDS
// slot c ^ (r&7). ds_read_b128 fragment reads then hit bank-quad
// ((fr&7)^C)*4 -> 8 distinct quads x 2 lanes = 2-way (free, m136).
// ---------------------------------------------------------------------------
#define BM 128
#define BN 128
#define BK 64

template <int K>
__device__ inline void gemm_tile(const u16* __restrict__ gA, const u16* __restrict__ gB,
                                 int m0, int n0, u16* As, u16* Bs, f32x4 (&acc)[4][4]) {
  const int tid = threadIdx.x;
  const int wave = tid >> 6, lane = tid & 63;
  const int wm = wave >> 1, wn = wave & 1;
  const int r8 = lane >> 3;                 // row within 8-row chunk
  const int kc = ((lane & 7) ^ r8) * 8;     // swizzled k element offset
  const int fr = lane & 15;                 // fragment row/col
  const int fx = fr & 7;                    // swizzle key for reads
  const int kq = lane >> 4;                 // fragment k-chunk 0..3

  auto stage = [&](int k0) {
#pragma unroll
    for (int t = 0; t < 4; ++t) {
      int chunk = wave * 4 + t;             // 16 chunks of 1KB per tile
      int row = chunk * 8 + r8;
      llds16(gA + (size_t)(m0 + row) * K + k0 + kc, (char*)As + chunk * 1024);
      llds16(gB + (size_t)(n0 + row) * K + k0 + kc, (char*)Bs + chunk * 1024);
    }
  };

  stage(0);                                 // overlap first staging with init
#pragma unroll
  for (int i = 0; i < 4; ++i)
#pragma unroll
    for (int j = 0; j < 4; ++j) acc[i][j] = f32x4{0.f, 0.f, 0.f, 0.f};

  for (int k0 = 0;;) {
    __syncthreads();                        // drains staging (vmcnt0 + barrier)
#pragma unroll
    for (int ks = 0; ks < 2; ++ks) {
      short8 a[4], b[4];
      const int slot = (((ks * 4 + kq) ^ fx)) * 8;
#pragma unroll
      for (int mt = 0; mt < 4; ++mt)
        a[mt] = *(const short8*)(As + (wm * 64 + mt * 16 + fr) * BK + slot);
#pragma unroll
      for (int nt = 0; nt < 4; ++nt)
        b[nt] = *(const short8*)(Bs + (wn * 64 + nt * 16 + fr) * BK + slot);
#pragma unroll
      for (int mt = 0; mt < 4; ++mt)
#pragma unroll
        for (int nt = 0; nt < 4; ++nt)
          acc[mt][nt] = __builtin_amdgcn_mfma_f32_16x16x32_bf16(a[mt], b[nt], acc[mt][nt], 0, 0, 0);
    }
    k0 += BK;
    if (k0 >= K) break;
    __syncthreads();                        // LDS reads done; safe to restage
    stage(k0);
  }
}

// QKV GEMM: C[bl][d] = xb[bl][c] * WqkvT[d][c] + bqkv[d], store bf16.
// 1D grid 1536 with bijective XCD chunking: XCD k owns m-panels [16k,16k+16)
// (= batch b=k rows) x all 12 n-tiles -> per-XCD L2 set = 16x64KB A-panels +
// full B (0.8MB) ~ 1.8 MB < 4 MB.
__global__ __launch_bounds__(256) void qkv_gemm(const u16* __restrict__ xb,
                                                const u16* __restrict__ wT,
                                                const float* __restrict__ bqkv,
                                                u16* __restrict__ qkv) {
  __shared__ __align__(16) u16 As[BM * BK];
  __shared__ __align__(16) u16 Bs[BN * BK];
  int id = blockIdx.x;                      // 1536 blocks, %8==0
  int swz = (id & 7) * 192 + (id >> 3);     // bijective XCD chunking (T1)
  int n0 = (swz % 12) * BN;
  int m0 = (swz / 12) * BM;
  f32x4 acc[4][4];
  gemm_tile<NHID_>(xb, wT, m0, n0, As, Bs, acc);
  const int lane = threadIdx.x & 63, wave = threadIdx.x >> 6;
  const int wm = wave >> 1, wn = wave & 1;
#pragma unroll
  for (int mt = 0; mt < 4; ++mt) {
    int row0 = m0 + wm * 64 + mt * 16 + (lane >> 4) * 4;
#pragma unroll
    for (int nt = 0; nt < 4; ++nt) {
      int col = n0 + wn * 64 + nt * 16 + (lane & 15);
      float bias = bqkv[col];
#pragma unroll
      for (int r = 0; r < 4; ++r)
        qkv[(size_t)(row0 + r) * QKVN + col] = f32_to_bf16(acc[mt][nt][r] + bias);
    }
  }
}

// Out GEMM (swapped): C[j][l] = WoT[j][c] * att[b*L+l][c] + bo[j], fp32 store
// to out[b][j][l] -- coalesced along l (MFMA C col = lane&15).
// 1D grid 2048 with XCD chunking: XCD k owns exactly b=k (256 blocks) ->
// per-XCD L2 set = att[b] (2MB, written by attn on the same XCD) + woT (2MB).
__global__ __launch_bounds__(256) void out_gemm(const u16* __restrict__ woT,
                                                const u16* __restrict__ att,
                                                const float* __restrict__ bo,
                                                float* __restrict__ out) {
  __shared__ __align__(16) u16 As[BM * BK];
  __shared__ __align__(16) u16 Bs[BN * BK];
  int id = blockIdx.x;                      // 2048 blocks, %8==0
  int swz = (id & 7) * 256 + (id >> 3);     // bijective XCD chunking (T1)
  int b = swz >> 8;
  int rem = swz & 255;
  int m0 = (rem >> 4) * BM;                 // j-panel
  int n0 = (rem & 15) * BN;                 // l-tile
  const u16* gB = att + (size_t)b * L_ * D_;
  f32x4 acc[4][4];
  gemm_tile<D_>(woT, gB, m0, n0, As, Bs, acc);
  const int lane = threadIdx.x & 63, wave = threadIdx.x >> 6;
  const int wm = wave >> 1, wn = wave & 1;
  float* outb = out + (size_t)b * DO_ * L_;
#pragma unroll
  for (int mt = 0; mt < 4; ++mt) {
    int row0 = m0 + wm * 64 + mt * 16 + (lane >> 4) * 4;
#pragma unroll
    for (int r = 0; r < 4; ++r) {
      float bias = bo[row0 + r];
#pragma unroll
      for (int nt = 0; nt < 4; ++nt) {
        int col = n0 + wn * 64 + nt * 16 + (lane & 15);
        outb[(size_t)(row0 + r) * L_ + col] = acc[mt][nt][r] + bias;
      }
    }
  }
}

// ---------------------------------------------------------------------------
// Windowed attention: one wave per (b,l). lane -> (head = lane>>3, 8 channels).
// OOB windows use k=v=0 and PARTICIPATE in softmax with score 0 (matches the
// reference's zero-padded extract_patches semantics). 512 threads = 8 waves.
// XCD-chunked like qkv/out: XCD k handles b=k -> reads qkv[b=k] (produced on
// XCD k) and writes att[b=k] (consumed on XCD k) through the same L2.
// ---------------------------------------------------------------------------
__global__ __launch_bounds__(512) void attn_kernel(const u16* __restrict__ qkv,
                                                   u16* __restrict__ att) {
  const int wave = threadIdx.x >> 6, lane = threadIdx.x & 63;
  int id = blockIdx.x;                      // 2048 blocks, %8==0
  int swz = (id & 7) * 256 + (id >> 3);     // bijective XCD chunking (T1)
  const int bl = swz * 8 + wave;
  const int l = bl & (L_ - 1);
  const int c0 = (lane >> 3) * 64 + (lane & 7) * 8;   // channel base, 8 per lane

  float q[8];
  load8(qkv + (size_t)bl * QKVN + c0, q);

  float kk[3][8], vv[3][8];
#pragma unroll
  for (int w = 0; w < 3; ++w) {
    int lw = l + w - 1;
    if (lw >= 0 && lw < L_) {
      const u16* base = qkv + (size_t)(bl + w - 1) * QKVN;
      load8(base + 512 + c0, kk[w]);
      load8(base + 1024 + c0, vv[w]);
    } else {
#pragma unroll
      for (int t = 0; t < 8; ++t) { kk[w][t] = 0.f; vv[w][t] = 0.f; }
    }
  }

  float s[3];
#pragma unroll
  for (int w = 0; w < 3; ++w) {
    float a = 0.f;
#pragma unroll
    for (int t = 0; t < 8; ++t) a = fmaf(q[t], kk[w][t], a);
    s[w] = a;
  }
  // reduce over the 8 lanes of this head (butterfly; all lanes end with sum)
#pragma unroll
  for (int off = 1; off < 8; off <<= 1) {
    s[0] += __shfl_xor(s[0], off);
    s[1] += __shfl_xor(s[1], off);
    s[2] += __shfl_xor(s[2], off);
  }
  s[0] *= 0.125f; s[1] *= 0.125f; s[2] *= 0.125f;   // 1/sqrt(64)

  float mx = fmaxf(s[0], fmaxf(s[1], s[2]));
  float e0 = __expf(s[0] - mx), e1 = __expf(s[1] - mx), e2 = __expf(s[2] - mx);
  float inv = 1.f / (e0 + e1 + e2);
  float a0 = e0 * inv, a1 = e1 * inv, a2 = e2 * inv;

  u16 o16[8];
#pragma unroll
  for (int t = 0; t < 8; ++t) {
    float o = a0 * vv[0][t] + a1 * vv[1][t] + a2 * vv[2][t];
    o16[t] = f32_to_bf16(o);
  }
  uint4 pk;
  pk.x = (unsigned)o16[0] | ((unsigned)o16[1] << 16);
  pk.y = (unsigned)o16[2] | ((unsigned)o16[3] << 16);
  pk.z = (unsigned)o16[4] | ((unsigned)o16[5] << 16);
  pk.w = (unsigned)o16[6] | ((unsigned)o16[7] << 16);
  *reinterpret_cast<uint4*>(att + (size_t)bl * D_ + c0) = pk;
}

// ---------------------------------------------------------------------------
extern "C" void kernel_launch(void* const* d_in, const int* in_sizes, int n_in,
                              void* d_out, int out_size, void* d_ws, size_t ws_size,
                              hipStream_t stream) {
  const float* x  = (const float*)d_in[0];
  const float* Wq = (const float*)d_in[1];
  const float* bq = (const float*)d_in[2];
  const float* Wk = (const float*)d_in[3];
  const float* bk = (const float*)d_in[4];
  const float* Wv = (const float*)d_in[5];
  const float* bv = (const float*)d_in[6];
  const float* Wo = (const float*)d_in[7];
  const float* bo = (const float*)d_in[8];
  float* out = (float*)d_out;

  char* ws = (char*)d_ws;
  // workspace layout (bytes)
  u16*   xb    = (u16*)(ws + 0);            //  16384x256  bf16  (8388608)
  u16*   wqkvT = (u16*)(ws + 8388608);      //  1536x256   bf16  (786432)
  u16*   woT   = (u16*)(ws + 9175040);      //  2048x512   bf16  (2097152)
  float* bqkv  = (float*)(ws + 11272192);   //  1536       f32   (6144)
  u16*   qkv   = (u16*)(ws + 11278336);     //  16384x1536 bf16  (50331648)
  u16*   att   = (u16*)(ws + 61609984);     //  16384x512  bf16  (16777216)
  // total ~78.4 MB

  // all transposes + bias in ONE launch (64x64 tiles, block (64,8))
  prep_all<<<PREP_NB, dim3(64, 8), 0, stream>>>(x, Wq, Wk, Wv, Wo, bq, bk, bv,
                                                xb, wqkvT, woT, bqkv);

  // QKV projection: [16384 x 1536] = xb [16384x256] * wqkvT^T
  qkv_gemm<<<(QKVN / BN) * ((B_ * L_) / BM), 256, 0, stream>>>(xb, wqkvT, bqkv, qkv);

  // windowed softmax attention -> att [16384x512] bf16
  attn_kernel<<<(B_ * L_) / 8, 512, 0, stream>>>(qkv, att);

  // output projection, transposed store: out[b][j][l]
  out_gemm<<<(L_ / BN) * (DO_ / BM) * B_, 256, 0, stream>>>(woT, att, bo, out);
}

// Round 5
// 217.140 us; speedup vs baseline: 1.1122x; 1.0139x over previous
//
#include <hip/hip_runtime.h>
#include <cstdint>
#include <cmath>

// Problem constants
#define B_    8
#define NHID_ 256
#define L_    2048
#define D_    512      // q/k/v channels (8 heads x 64)
#define DO_   2048     // output channels
#define QKVN  1536     // concat q|k|v

using u16    = unsigned short;
using short8 = __attribute__((ext_vector_type(8))) short;  // 8 bf16 (4 VGPRs)
using f32x4  = __attribute__((ext_vector_type(4))) float;  // 4 fp32 acc

typedef __attribute__((address_space(1))) void gv_t;
typedef __attribute__((address_space(3))) void lv_t;

__device__ inline void llds16(const void* g, void* l) {
  // async global->LDS, 16B/lane; LDS dest = wave-uniform base + lane*16
  __builtin_amdgcn_global_load_lds((const gv_t*)g, (lv_t*)l, 16, 0, 0);
}

__device__ inline u16 f32_to_bf16(float f) {
  unsigned u = __float_as_uint(f);
  u += 0x7fffu + ((u >> 16) & 1u);   // RNE (values finite)
  return (u16)(u >> 16);
}

__device__ inline void load8(const u16* p, float f[8]) {
  uint4 u = *reinterpret_cast<const uint4*>(p);
  f[0] = __uint_as_float(u.x << 16); f[1] = __uint_as_float(u.x & 0xffff0000u);
  f[2] = __uint_as_float(u.y << 16); f[3] = __uint_as_float(u.y & 0xffff0000u);
  f[4] = __uint_as_float(u.z << 16); f[5] = __uint_as_float(u.z & 0xffff0000u);
  f[6] = __uint_as_float(u.w << 16); f[7] = __uint_as_float(u.w & 0xffff0000u);
}

// ---------------------------------------------------------------------------
// prep (single launch): fp32 [R][C] -> bf16 [C][R] transposes for x and all
// weights, plus bias concat. 64x64 tiles, block (64,8): 256B coalesced fp32
// loads, 128B bf16 store rows. LDS [64][65]: column reads hit (tx+c)%32 ->
// 2-way bank alias = free.
// ---------------------------------------------------------------------------
template <int R, int C>
__device__ inline void t64(const float* __restrict__ src, u16* __restrict__ dst,
                           int id, float (*tile)[65]) {
  constexpr int TPR = C / 64;              // tiles along cols
  constexpr int PER = (R / 64) * TPR;      // tiles per z-slice
  int z = id / PER, rem = id % PER;
  int ry = rem / TPR, cx = rem % TPR;
  src += (size_t)z * R * C;
  dst += (size_t)z * R * C;
  int c0 = cx * 64, r0 = ry * 64;
  int tx = threadIdx.x, ty = threadIdx.y;
#pragma unroll
  for (int i = 0; i < 8; ++i)
    tile[ty + i * 8][tx] = src[(size_t)(r0 + ty + i * 8) * C + c0 + tx];
  __syncthreads();
#pragma unroll
  for (int i = 0; i < 8; ++i)
    dst[(size_t)(c0 + ty + i * 8) * R + r0 + tx] = f32_to_bf16(tile[tx][ty + i * 8]);
}

// block-id ranges (64x64 tiles)
#define PREP_WQ   1024     // x: 8 * (256/64) * (2048/64) = 1024 tiles
#define PREP_WK   1056     // Wq: (256/64)*(512/64) = 32 tiles
#define PREP_WV   1088
#define PREP_WO   1120
#define PREP_BIAS 1376     // Wo: (512/64)*(2048/64) = 256 tiles
#define PREP_NB   1379     // bias: 1536/512 = 3 blocks

__global__ void prep_all(const float* __restrict__ x,
                         const float* __restrict__ Wq, const float* __restrict__ Wk,
                         const float* __restrict__ Wv, const float* __restrict__ Wo,
                         const float* __restrict__ bq, const float* __restrict__ bk,
                         const float* __restrict__ bv,
                         u16* __restrict__ xb, u16* __restrict__ wqkvT,
                         u16* __restrict__ woT, float* __restrict__ bqkv) {
  __shared__ float tile[64][65];
  int bid = blockIdx.x;
  if (bid < PREP_WQ) {
    t64<NHID_, L_>(x, xb, bid, tile);
  } else if (bid < PREP_WK) {
    t64<NHID_, D_>(Wq, wqkvT, bid - PREP_WQ, tile);
  } else if (bid < PREP_WV) {
    t64<NHID_, D_>(Wk, wqkvT + 512 * NHID_, bid - PREP_WK, tile);
  } else if (bid < PREP_WO) {
    t64<NHID_, D_>(Wv, wqkvT + 1024 * NHID_, bid - PREP_WV, tile);
  } else if (bid < PREP_BIAS) {
    t64<D_, DO_>(Wo, woT, bid - PREP_WO, tile);
  } else {
    int d = (bid - PREP_BIAS) * 512 + threadIdx.y * 64 + threadIdx.x;
    float v = (d < 512) ? bq[d] : (d < 1024 ? bk[d - 512] : bv[d - 1024]);
    bqkv[d] = v;
  }
}

// ---------------------------------------------------------------------------
// m97-style A*B^T GEMM core with XOR-swizzled LDS staging (round-0 proven).
// A [M][K], B [N][K] bf16 row-major (K contiguous), 128x128 tile, BK=64,
// 256 threads = 4 waves (2x2), 4x4 16x16x32 MFMA per wave. 32 KiB LDS ->
// 3+ blocks/CU; inter-block wave overlap hides the barrier drain (m114).
//
// Swizzle: global k-chunk c (8 elems = 16B) of tile-row r is staged at LDS
// slot c ^ (r&7). ds_read_b128 fragment reads then hit bank-quad
// ((fr&7)^C)*4 -> 8 distinct quads x 2 lanes = 2-way (free, m136).
// ---------------------------------------------------------------------------
#define BM 128
#define BN 128
#define BK 64

template <int K>
__device__ inline void gemm_tile(const u16* __restrict__ gA, const u16* __restrict__ gB,
                                 int m0, int n0, u16* As, u16* Bs, f32x4 (&acc)[4][4]) {
  const int tid = threadIdx.x;
  const int wave = tid >> 6, lane = tid & 63;
  const int wm = wave >> 1, wn = wave & 1;
  const int r8 = lane >> 3;                 // row within 8-row chunk
  const int kc = ((lane & 7) ^ r8) * 8;     // swizzled k element offset
  const int fr = lane & 15;                 // fragment row/col
  const int fx = fr & 7;                    // swizzle key for reads
  const int kq = lane >> 4;                 // fragment k-chunk 0..3

  auto stage = [&](int k0) {
#pragma unroll
    for (int t = 0; t < 4; ++t) {
      int chunk = wave * 4 + t;             // 16 chunks of 1KB per tile
      int row = chunk * 8 + r8;
      llds16(gA + (size_t)(m0 + row) * K + k0 + kc, (char*)As + chunk * 1024);
      llds16(gB + (size_t)(n0 + row) * K + k0 + kc, (char*)Bs + chunk * 1024);
    }
  };

  stage(0);                                 // overlap first staging with init
#pragma unroll
  for (int i = 0; i < 4; ++i)
#pragma unroll
    for (int j = 0; j < 4; ++j) acc[i][j] = f32x4{0.f, 0.f, 0.f, 0.f};

  for (int k0 = 0;;) {
    __syncthreads();                        // drains staging (vmcnt0 + barrier)
#pragma unroll
    for (int ks = 0; ks < 2; ++ks) {
      short8 a[4], b[4];
      const int slot = (((ks * 4 + kq) ^ fx)) * 8;
#pragma unroll
      for (int mt = 0; mt < 4; ++mt)
        a[mt] = *(const short8*)(As + (wm * 64 + mt * 16 + fr) * BK + slot);
#pragma unroll
      for (int nt = 0; nt < 4; ++nt)
        b[nt] = *(const short8*)(Bs + (wn * 64 + nt * 16 + fr) * BK + slot);
#pragma unroll
      for (int mt = 0; mt < 4; ++mt)
#pragma unroll
        for (int nt = 0; nt < 4; ++nt)
          acc[mt][nt] = __builtin_amdgcn_mfma_f32_16x16x32_bf16(a[mt], b[nt], acc[mt][nt], 0, 0, 0);
    }
    k0 += BK;
    if (k0 >= K) break;
    __syncthreads();                        // LDS reads done; safe to restage
    stage(k0);
  }
}

// QKV GEMM: C[bl][d] = xb[bl][c] * WqkvT[d][c] + bqkv[d], store bf16.
// 1D grid 1536 with bijective XCD chunking: XCD k owns m-panels [16k,16k+16)
// (= batch b=k rows) x all 12 n-tiles -> per-XCD L2 set = 16x64KB A-panels +
// full B (0.8MB) ~ 1.8 MB < 4 MB.
__global__ __launch_bounds__(256) void qkv_gemm(const u16* __restrict__ xb,
                                                const u16* __restrict__ wT,
                                                const float* __restrict__ bqkv,
                                                u16* __restrict__ qkv) {
  __shared__ __align__(16) u16 As[BM * BK];
  __shared__ __align__(16) u16 Bs[BN * BK];
  int id = blockIdx.x;                      // 1536 blocks, %8==0
  int swz = (id & 7) * 192 + (id >> 3);     // bijective XCD chunking (T1)
  int n0 = (swz % 12) * BN;
  int m0 = (swz / 12) * BM;
  f32x4 acc[4][4];
  gemm_tile<NHID_>(xb, wT, m0, n0, As, Bs, acc);
  const int lane = threadIdx.x & 63, wave = threadIdx.x >> 6;
  const int wm = wave >> 1, wn = wave & 1;
#pragma unroll
  for (int mt = 0; mt < 4; ++mt) {
    int row0 = m0 + wm * 64 + mt * 16 + (lane >> 4) * 4;
#pragma unroll
    for (int nt = 0; nt < 4; ++nt) {
      int col = n0 + wn * 64 + nt * 16 + (lane & 15);
      float bias = bqkv[col];
#pragma unroll
      for (int r = 0; r < 4; ++r)
        qkv[(size_t)(row0 + r) * QKVN + col] = f32_to_bf16(acc[mt][nt][r] + bias);
    }
  }
}

// Out GEMM (swapped): C[j][l] = WoT[j][c] * att[b*L+l][c] + bo[j], fp32 store
// to out[b][j][l] -- coalesced along l (MFMA C col = lane&15).
// 1D grid 2048 with XCD chunking: XCD k owns exactly b=k (256 blocks) ->
// per-XCD L2 set = att[b] (2MB, written by attn on the same XCD) + woT (2MB).
__global__ __launch_bounds__(256) void out_gemm(const u16* __restrict__ woT,
                                                const u16* __restrict__ att,
                                                const float* __restrict__ bo,
                                                float* __restrict__ out) {
  __shared__ __align__(16) u16 As[BM * BK];
  __shared__ __align__(16) u16 Bs[BN * BK];
  int id = blockIdx.x;                      // 2048 blocks, %8==0
  int swz = (id & 7) * 256 + (id >> 3);     // bijective XCD chunking (T1)
  int b = swz >> 8;
  int rem = swz & 255;
  int m0 = (rem >> 4) * BM;                 // j-panel
  int n0 = (rem & 15) * BN;                 // l-tile
  const u16* gB = att + (size_t)b * L_ * D_;
  f32x4 acc[4][4];
  gemm_tile<D_>(woT, gB, m0, n0, As, Bs, acc);
  const int lane = threadIdx.x & 63, wave = threadIdx.x >> 6;
  const int wm = wave >> 1, wn = wave & 1;
  float* outb = out + (size_t)b * DO_ * L_;
#pragma unroll
  for (int mt = 0; mt < 4; ++mt) {
    int row0 = m0 + wm * 64 + mt * 16 + (lane >> 4) * 4;
#pragma unroll
    for (int r = 0; r < 4; ++r) {
      float bias = bo[row0 + r];
#pragma unroll
      for (int nt = 0; nt < 4; ++nt) {
        int col = n0 + wn * 64 + nt * 16 + (lane & 15);
        outb[(size_t)(row0 + r) * L_ + col] = acc[mt][nt][r] + bias;
      }
    }
  }
}

// ---------------------------------------------------------------------------
// Windowed attention, 2 rows per wave: wave handles global rows 2g, 2g+1.
// Window union = k/v rows 2g-1 .. 2g+2 -> 4 k-loads + 4 v-loads + 2 q-loads
// per 2 outputs (5 loads/row vs 7 in the 1-row version), 2 independent
// softmax chains per wave (2x ILP). lane -> (head = lane>>3, 8 channels).
// OOB window rows use k=v=0 and PARTICIPATE in softmax with score 0 (matches
// the reference's zero-padded extract_patches semantics).
// 1024 blocks x 512 threads; XCD-chunked so XCD k handles batch b=k.
// ---------------------------------------------------------------------------
__global__ __launch_bounds__(512) void attn_kernel(const u16* __restrict__ qkv,
                                                   u16* __restrict__ att) {
  const int wave = threadIdx.x >> 6, lane = threadIdx.x & 63;
  int id = blockIdx.x;                      // 1024 blocks, %8==0
  int swz = (id & 7) * 128 + (id >> 3);     // bijective XCD chunking (T1)
  const int g = swz * 8 + wave;             // 8192 groups of 2 rows
  const int gr0 = g * 2;                    // first global row (even)
  const int l0 = gr0 & (L_ - 1);            // local l of row 0 (even)
  const int c0 = (lane >> 3) * 64 + (lane & 7) * 8;   // channel base, 8 per lane

  float q[2][8];
  load8(qkv + (size_t)gr0 * QKVN + c0, q[0]);
  load8(qkv + (size_t)(gr0 + 1) * QKVN + c0, q[1]);

  // k/v rows gr0-1 .. gr0+2  (j = 0..3)
  float kk[4][8], vv[4][8];
#pragma unroll
  for (int j = 0; j < 4; ++j) {
    bool valid = !(j == 0 && l0 == 0) && !(j == 3 && l0 == L_ - 2);
    if (valid) {
      const u16* base = qkv + (size_t)(gr0 - 1 + j) * QKVN;
      load8(base + 512 + c0, kk[j]);
      load8(base + 1024 + c0, vv[j]);
    } else {
#pragma unroll
      for (int t = 0; t < 8; ++t) { kk[j][t] = 0.f; vv[j][t] = 0.f; }
    }
  }

  // scores: row r window w uses k row j = r + w
  float s[2][3];
#pragma unroll
  for (int r = 0; r < 2; ++r)
#pragma unroll
    for (int w = 0; w < 3; ++w) {
      float a = 0.f;
#pragma unroll
      for (int t = 0; t < 8; ++t) a = fmaf(q[r][t], kk[r + w][t], a);
      s[r][w] = a;
    }
  // reduce over the 8 lanes of this head (butterfly; all lanes end with sum)
#pragma unroll
  for (int off = 1; off < 8; off <<= 1) {
#pragma unroll
    for (int r = 0; r < 2; ++r) {
      s[r][0] += __shfl_xor(s[r][0], off);
      s[r][1] += __shfl_xor(s[r][1], off);
      s[r][2] += __shfl_xor(s[r][2], off);
    }
  }

#pragma unroll
  for (int r = 0; r < 2; ++r) {
    float s0 = s[r][0] * 0.125f, s1 = s[r][1] * 0.125f, s2 = s[r][2] * 0.125f;
    float mx = fmaxf(s0, fmaxf(s1, s2));
    float e0 = __expf(s0 - mx), e1 = __expf(s1 - mx), e2 = __expf(s2 - mx);
    float inv = 1.f / (e0 + e1 + e2);
    float a0 = e0 * inv, a1 = e1 * inv, a2 = e2 * inv;

    u16 o16[8];
#pragma unroll
    for (int t = 0; t < 8; ++t) {
      float o = a0 * vv[r][t] + a1 * vv[r + 1][t] + a2 * vv[r + 2][t];
      o16[t] = f32_to_bf16(o);
    }
    uint4 pk;
    pk.x = (unsigned)o16[0] | ((unsigned)o16[1] << 16);
    pk.y = (unsigned)o16[2] | ((unsigned)o16[3] << 16);
    pk.z = (unsigned)o16[4] | ((unsigned)o16[5] << 16);
    pk.w = (unsigned)o16[6] | ((unsigned)o16[7] << 16);
    *reinterpret_cast<uint4*>(att + (size_t)(gr0 + r) * D_ + c0) = pk;
  }
}

// ---------------------------------------------------------------------------
extern "C" void kernel_launch(void* const* d_in, const int* in_sizes, int n_in,
                              void* d_out, int out_size, void* d_ws, size_t ws_size,
                              hipStream_t stream) {
  const float* x  = (const float*)d_in[0];
  const float* Wq = (const float*)d_in[1];
  const float* bq = (const float*)d_in[2];
  const float* Wk = (const float*)d_in[3];
  const float* bk = (const float*)d_in[4];
  const float* Wv = (const float*)d_in[5];
  const float* bv = (const float*)d_in[6];
  const float* Wo = (const float*)d_in[7];
  const float* bo = (const float*)d_in[8];
  float* out = (float*)d_out;

  char* ws = (char*)d_ws;
  // workspace layout (bytes)
  u16*   xb    = (u16*)(ws + 0);            //  16384x256  bf16  (8388608)
  u16*   wqkvT = (u16*)(ws + 8388608);      //  1536x256   bf16  (786432)
  u16*   woT   = (u16*)(ws + 9175040);      //  2048x512   bf16  (2097152)
  float* bqkv  = (float*)(ws + 11272192);   //  1536       f32   (6144)
  u16*   qkv   = (u16*)(ws + 11278336);     //  16384x1536 bf16  (50331648)
  u16*   att   = (u16*)(ws + 61609984);     //  16384x512  bf16  (16777216)
  // total ~78.4 MB

  // all transposes + bias in ONE launch (64x64 tiles, block (64,8))
  prep_all<<<PREP_NB, dim3(64, 8), 0, stream>>>(x, Wq, Wk, Wv, Wo, bq, bk, bv,
                                                xb, wqkvT, woT, bqkv);

  // QKV projection: [16384 x 1536] = xb [16384x256] * wqkvT^T
  qkv_gemm<<<(QKVN / BN) * ((B_ * L_) / BM), 256, 0, stream>>>(xb, wqkvT, bqkv, qkv);

  // windowed softmax attention -> att [16384x512] bf16 (2 rows/wave)
  attn_kernel<<<(B_ * L_) / 16, 512, 0, stream>>>(qkv, att);

  // output projection, transposed store: out[b][j][l]
  out_gemm<<<(L_ / BN) * (DO_ / BM) * B_, 256, 0, stream>>>(woT, att, bo, out);
}